// Round 13
// baseline (506.183 us; speedup 1.0000x reference)
//
#include <hip/hip_runtime.h>
#include <hip/hip_bf16.h>

// Round 13: r12 + wave-private LDS staging for QK K-loads.
// Mechanism (T3/T4): global_load_lds (width 16) + counted s_waitcnt vmcnt(8)
// keeps 8 K-loads in flight across the QK loop at zero VGPR cost; the r12
// direct-to-register loads forced the compiler to serialize on register
// waitcnts (all pipes idle, latency-bound). 3-deep wave-private buffers ->
// no new barriers. Math order bit-identical to r12 (absmax must not move).

using short8   = __attribute__((ext_vector_type(8))) short;
using short4v  = __attribute__((ext_vector_type(4))) short;
using ushort4v = __attribute__((ext_vector_type(4))) unsigned short;
using f32x4    = __attribute__((ext_vector_type(4))) float;

#define L_T   2048
#define B_T   4
#define HID_T 512
#define HD_T  64
#define LQ_T  128
#define L0_T  1920   // L - LQ

__device__ __forceinline__ float b2f(unsigned short u){
  return __uint_as_float(((unsigned int)u) << 16);
}
__device__ __forceinline__ unsigned short f2b(float f){  // RNE float->bf16
  unsigned int u = __float_as_uint(f);
  u += 0x7FFFu + ((u >> 16) & 1u);
  return (unsigned short)(u >> 16);
}
__device__ __forceinline__ f32x4 mfma16(short8 a, short8 b, f32x4 c){
  return __builtin_amdgcn_mfma_f32_16x16x32_bf16(a, b, c, 0, 0, 0);
}
#if __has_builtin(__builtin_amdgcn_mfma_f32_16x16x16bf16_1k)
__device__ __forceinline__ f32x4 mfma16k16(short4v a, short4v b, f32x4 c){
  return __builtin_amdgcn_mfma_f32_16x16x16bf16_1k(a, b, c, 0, 0, 0);
}
#else
__device__ __forceinline__ f32x4 mfma16k16(short4v a, short4v b, f32x4 c){
  f32x4 d;
  asm("v_mfma_f32_16x16x16_bf16 %0, %1, %2, %0"
      : "=v"(d) : "v"(a), "v"(b), "0"(c));
  return d;
}
#endif

// ---------- split 4 weight matrices f32 -> packed bf16 hi/lo fragments ----
__global__ __launch_bounds__(256) void k_splitW(const float* __restrict__ w0,
                                                const float* __restrict__ w1,
                                                const float* __restrict__ w2,
                                                const float* __restrict__ w3,
                                                unsigned short* __restrict__ hi,
                                                unsigned short* __restrict__ lo)
{
  int wid = blockIdx.y;
  const float* src = (wid == 0) ? w0 : (wid == 1) ? w1 : (wid == 2) ? w2 : w3;
  int chunk = blockIdx.x * 256 + threadIdx.x;      // 65536 chunks
  int o = chunk >> 7;
  int hpos = (chunk & 127) * 4;
  f32x4 v = ((const f32x4*)src)[chunk];
  ushort4v h4, l4;
  #pragma unroll
  for (int e = 0; e < 4; e++){
    unsigned short h = f2b(v[e]);
    h4[e] = h;
    l4[e] = f2b(v[e] - b2f(h));
  }
  size_t idx = ((size_t)(wid * 512 + (o >> 4) * 16 + (hpos >> 5))) * 512
             + (((hpos & 31) >> 3) * 16 + (o & 15)) * 8 + (hpos & 7);
  *(ushort4v*)(hi + idx) = h4;
  *(ushort4v*)(lo + idx) = l4;
}

// ---------- fused projections: q, k, v in ONE kernel ----------
__global__ __launch_bounds__(256) void k_proj3(const float* __restrict__ Xq,
                                               const float* __restrict__ Xk,
                                               const float* __restrict__ Xv,
                                               const unsigned short* __restrict__ WhA,
                                               const unsigned short* __restrict__ WlA,
                                               unsigned short* __restrict__ qhp,
                                               unsigned short* __restrict__ qlp,
                                               unsigned short* __restrict__ khp,
                                               unsigned short* __restrict__ klp,
                                               unsigned short* __restrict__ vpk)
{
  int sel = blockIdx.x >> 10;              // 0=q, 1=k, 2=v
  int bx  = blockIdx.x & 1023;
  const float* X = (sel == 0) ? Xq : (sel == 1) ? Xk : Xv;
  const short* WH = (const short*)WhA + (size_t)sel * 262144;
  const short* WL = (const short*)WlA + (size_t)sel * 262144;
  unsigned short* ohi = (sel == 0) ? qhp : khp;
  unsigned short* olo = (sel == 0) ? qlp : klp;

  int wv = threadIdx.x >> 6, lane = threadIdx.x & 63;
  int tid = bx * 4 + wv;                   // 4096 wave-tiles per sel
  int mt = tid >> 3, nt = tid & 7;
  int row0 = mt * 16, col0 = nt * 64;
  int lhi = lane >> 4, llo = lane & 15;
  int arow = row0 + llo;
  f32x4 acc[4] = {{0,0,0,0},{0,0,0,0},{0,0,0,0},{0,0,0,0}};
  #pragma unroll 4
  for (int k0 = 0; k0 < 512; k0 += 32){
    const float* ap = X + (size_t)arow * 512 + k0 + lhi * 8;
    f32x4 a01 = *(const f32x4*)ap;
    f32x4 a23 = *(const f32x4*)(ap + 4);
    short8 ah, al;
    #pragma unroll
    for (int e = 0; e < 4; e++){
      unsigned short h0 = f2b(a01[e]);
      ah[e] = (short)h0;  al[e] = (short)f2b(a01[e] - b2f(h0));
      unsigned short h1 = f2b(a23[e]);
      ah[e + 4] = (short)h1;  al[e + 4] = (short)f2b(a23[e] - b2f(h1));
    }
    int kk = k0 >> 5;
    #pragma unroll
    for (int cb = 0; cb < 4; cb++){
      size_t bidx = (size_t)(((col0 >> 4) + cb) * 16 + kk) * 512 + lane * 8;
      short8 bh = *(const short8*)(WH + bidx);
      short8 bl = *(const short8*)(WL + bidx);
      acc[cb] = mfma16(ah, bh, acc[cb]);
      acc[cb] = mfma16(al, bh, acc[cb]);
      acc[cb] = mfma16(ah, bl, acc[cb]);
    }
  }
  #pragma unroll
  for (int cb = 0; cb < 4; cb++){
    #pragma unroll
    for (int r = 0; r < 4; r++){
      int row = row0 + lhi * 4 + r;        // flat (l,b)
      int o   = col0 + cb * 16 + llo;
      int l = row >> 2, bb = row & 3;
      int n = bb * 8 + (o >> 6), d = o & 63;
      float v = acc[cb][r];
      if (sel != 2){
        size_t idx = ((size_t)(n * 128 + (l >> 4)) * 2 + (d >> 5)) * 512
                   + (((d & 31) >> 3) * 16 + (l & 15)) * 8 + (d & 7);
        unsigned short h = f2b(v);
        ohi[idx] = h;
        olo[idx] = f2b(v - b2f(h));
      } else {
        int m = l;
        size_t idx = (((size_t)(n * 128 + (m >> 4)) * 4) + (d >> 4)) * 256
                   + ((m & 15) >> 2) * 64 + (d & 15) * 4 + (m & 3);
        vpk[idx] = f2b(v);
      }
    }
  }
}

// ---------- merged t + bias:  per block (bb, i) ----------
__global__ __launch_bounds__(256) void k_tb(const unsigned short* __restrict__ qhp,
                                            const unsigned short* __restrict__ qlp,
                                            const float* __restrict__ Wk,
                                            const float* __restrict__ qrem,
                                            float* __restrict__ bias)
{
  int bb = blockIdx.x & 3, i = blockIdx.x >> 2;
  __shared__ float qv[8][64];
  __shared__ float ts[8][512];
  for (int idx = threadIdx.x; idx < 512; idx += 256){
    int kh = idx >> 6, d = idx & 63;
    int n = bb * 8 + kh;
    int row = L0_T + i;
    size_t qidx = ((size_t)(n * 128 + (row >> 4)) * 2 + (d >> 5)) * 512
                + (((d & 31) >> 3) * 16 + (row & 15)) * 8 + (d & 7);
    qv[kh][d] = b2f(qhp[qidx]) + b2f(qlp[qidx]);
  }
  __syncthreads();
  {
    int kh = threadIdx.x >> 5, h0 = (threadIdx.x & 31) * 16;
    f32x4 a0 = {0,0,0,0}, a1 = {0,0,0,0}, a2 = {0,0,0,0}, a3 = {0,0,0,0};
    for (int d = 0; d < 64; d++){
      float qd = qv[kh][d];
      const float* wr = Wk + (size_t)(kh * 64 + d) * 512 + h0;
      a0 += qd * *(const f32x4*)(wr);
      a1 += qd * *(const f32x4*)(wr + 4);
      a2 += qd * *(const f32x4*)(wr + 8);
      a3 += qd * *(const f32x4*)(wr + 12);
    }
    *(f32x4*)&ts[kh][h0]      = a0;
    *(f32x4*)&ts[kh][h0 + 4]  = a1;
    *(f32x4*)&ts[kh][h0 + 8]  = a2;
    *(f32x4*)&ts[kh][h0 + 12] = a3;
  }
  __syncthreads();
  int wv = threadIdx.x >> 6, lane = threadIdx.x & 63;
  for (int j = wv; j < 128; j += 4){
    const float* qr = qrem + (((size_t)i * LQ_T + j) * B_T + bb) * 512;
    f32x4 v0 = *(const f32x4*)(qr + lane * 4);
    f32x4 v1 = *(const f32x4*)(qr + 256 + lane * 4);
    float pl[8];
    #pragma unroll
    for (int kh = 0; kh < 8; kh++){
      f32x4 t0 = *(const f32x4*)&ts[kh][lane * 4];
      f32x4 t1 = *(const f32x4*)&ts[kh][256 + lane * 4];
      pl[kh] = v0[0]*t0[0] + v0[1]*t0[1] + v0[2]*t0[2] + v0[3]*t0[3]
             + v1[0]*t1[0] + v1[1]*t1[1] + v1[2]*t1[2] + v1[3]*t1[3];
    }
    #pragma unroll
    for (int kh = 0; kh < 8; kh++){
      float s = pl[kh];
      #pragma unroll
      for (int msk = 1; msk < 64; msk <<= 1) s += __shfl_xor(s, msk);
      pl[kh] = s;
    }
    if (lane == 0){
      #pragma unroll
      for (int kh = 0; kh < 8; kh++)
        bias[((size_t)(bb * 8 + kh) * LQ_T + i) * LQ_T + j] = pl[kh];
    }
  }
}

// ---------- fused QK^T(swapped) + bias + mask + softmax + p-store + PV ----------
// r12 structure; QK K-loads staged through wave-private 3-deep LDS buffers
// via global_load_lds (width 16) + counted vmcnt(8). No new barriers.
__attribute__((amdgpu_waves_per_eu(2, 2)))
__global__ __launch_bounds__(512) void k_attn(
    const unsigned short* __restrict__ qhp, const unsigned short* __restrict__ qlp,
    const unsigned short* __restrict__ khp, const unsigned short* __restrict__ klp,
    const float* __restrict__ bias, const float* __restrict__ kpm,
    const unsigned short* __restrict__ vpk,
    float* __restrict__ attnF, float* __restrict__ outbk)
{
  __shared__ __attribute__((aligned(16))) short kvb[8][3][4][512];  // 96 KB staging
  __shared__ __attribute__((aligned(16))) float pf[8 * 1024];       // 32 KB
  __shared__ float2 red2[2 * 128];                                  // 2 KB
  const int w = threadIdx.x >> 6, lane = threadIdx.x & 63;
  const int lhi = lane >> 4, llo = lane & 15;

  for (int j = 0; j < 8; ++j){
    const int p = blockIdx.x + (j << 8);   // 4 heads live per phase
    const int n = p >> 6, rbp = p & 63;
    const int rbA = rbp * 2, rbB = rbA + 1;
    const int row0A = rbA * 16, row0B = rbB * 16, bb = n >> 3;

    const short* QHA = (const short*)qhp + ((size_t)(n * 128 + rbA) * 2) * 512 + lane * 8;
    const short* QLA = (const short*)qlp + ((size_t)(n * 128 + rbA) * 2) * 512 + lane * 8;
    const short* QHB = (const short*)qhp + ((size_t)(n * 128 + rbB) * 2) * 512 + lane * 8;
    const short* QLB = (const short*)qlp + ((size_t)(n * 128 + rbB) * 2) * 512 + lane * 8;
    short8 qhA0 = *(const short8*)(QHA);
    short8 qhA1 = *(const short8*)(QHA + 512);
    short8 qlA0 = *(const short8*)(QLA);
    short8 qlA1 = *(const short8*)(QLA + 512);
    short8 qhB0 = *(const short8*)(QHB);
    short8 qhB1 = *(const short8*)(QHB + 512);
    short8 qlB0 = *(const short8*)(QLB);
    short8 qlB1 = *(const short8*)(QLB + 512);
    const short* KH = (const short*)khp + (size_t)n * 131072 + w * 1024 + lane * 8;
    const short* KL = (const short*)klp + (size_t)n * 131072 + w * 1024 + lane * 8;

    // K staging: 4 chunks/t, 16B per lane, linear LDS dest (wave-uniform base).
    #define STAGE_K(tt, bq) do {                                               \
      __builtin_amdgcn_global_load_lds(                                        \
        (const __attribute__((address_space(1))) unsigned int*)(KH + (tt) * 8192),        \
        (__attribute__((address_space(3))) unsigned int*)&kvb[w][bq][0][0], 16, 0, 0);    \
      __builtin_amdgcn_global_load_lds(                                        \
        (const __attribute__((address_space(1))) unsigned int*)(KH + (tt) * 8192 + 512),  \
        (__attribute__((address_space(3))) unsigned int*)&kvb[w][bq][1][0], 16, 0, 0);    \
      __builtin_amdgcn_global_load_lds(                                        \
        (const __attribute__((address_space(1))) unsigned int*)(KL + (tt) * 8192),        \
        (__attribute__((address_space(3))) unsigned int*)&kvb[w][bq][2][0], 16, 0, 0);    \
      __builtin_amdgcn_global_load_lds(                                        \
        (const __attribute__((address_space(1))) unsigned int*)(KL + (tt) * 8192 + 512),  \
        (__attribute__((address_space(3))) unsigned int*)&kvb[w][bq][3][0], 16, 0, 0);    \
    } while (0)

    STAGE_K(0, 0);
    STAGE_K(1, 1);

    // ---- QK^T: tile = w + 8t; staged K pair -> 12 MFMA (order = r12) ----
    float svA[16][4], svB[16][4];
    #pragma unroll
    for (int t = 0; t < 16; t++){
      const int cur = t % 3;
      if (t < 14){
        STAGE_K(t + 2, ((t + 2) % 3));
        asm volatile("s_waitcnt vmcnt(8)" ::: "memory");   // t's 4 loads landed
      } else if (t == 14){
        asm volatile("s_waitcnt vmcnt(4)" ::: "memory");
      } else {
        asm volatile("s_waitcnt vmcnt(0)" ::: "memory");
      }
      short8 kh0v = *(const short8*)&kvb[w][cur][0][lane * 8];
      short8 kh1v = *(const short8*)&kvb[w][cur][1][lane * 8];
      short8 kl0v = *(const short8*)&kvb[w][cur][2][lane * 8];
      short8 kl1v = *(const short8*)&kvb[w][cur][3][lane * 8];
      f32x4 aA = {0.f, 0.f, 0.f, 0.f};
      f32x4 aB = {0.f, 0.f, 0.f, 0.f};
      aA = mfma16(kh0v, qhA0, aA);
      aA = mfma16(kl0v, qhA0, aA);
      aA = mfma16(kh0v, qlA0, aA);
      aA = mfma16(kh1v, qhA1, aA);
      aA = mfma16(kl1v, qhA1, aA);
      aA = mfma16(kh1v, qlA1, aA);
      aB = mfma16(kh0v, qhB0, aB);
      aB = mfma16(kl0v, qhB0, aB);
      aB = mfma16(kh0v, qlB0, aB);
      aB = mfma16(kh1v, qhB1, aB);
      aB = mfma16(kl1v, qhB1, aB);
      aB = mfma16(kh1v, qlB1, aB);
      if (t == 15 && rbp >= 60){           // tiles 120..127 = (t=15, all w)
        int j0 = w * 16 + lhi * 4;
        int iA = row0A - L0_T + llo;
        int iB = row0B - L0_T + llo;
        aA += *(const f32x4*)(bias + ((size_t)(n * 128 + iA)) * 128 + j0);
        aB += *(const f32x4*)(bias + ((size_t)(n * 128 + iB)) * 128 + j0);
      }
      f32x4 mkv = *(const f32x4*)(kpm + bb * 2048 + (w + t * 8) * 16 + lhi * 4);
      #pragma unroll
      for (int r = 0; r < 4; r++){
        float mk = (mkv[r] != 0.f) ? -__builtin_inff() : 0.f;
        svA[t][r] = aA[r] * 0.125f + mk;
        svB[t][r] = aB[r] * 0.125f + mk;
      }
    }
    #undef STAGE_K

    // ---- wave-level (max, expsum) per q = llo ----
    float pmA = svA[0][0], pmB = svB[0][0];
    #pragma unroll
    for (int t = 0; t < 16; t++)
      #pragma unroll
      for (int r = 0; r < 4; r++){
        pmA = fmaxf(pmA, svA[t][r]);
        pmB = fmaxf(pmB, svB[t][r]);
      }
    pmA = fmaxf(pmA, __shfl_xor(pmA, 16));
    pmA = fmaxf(pmA, __shfl_xor(pmA, 32));
    pmB = fmaxf(pmB, __shfl_xor(pmB, 16));
    pmB = fmaxf(pmB, __shfl_xor(pmB, 32));
    float esA = 0.f, esB = 0.f;
    #pragma unroll
    for (int t = 0; t < 16; t++)
      #pragma unroll
      for (int r = 0; r < 4; r++){
        float eA = __expf(svA[t][r] - pmA);
        float eB = __expf(svB[t][r] - pmB);
        svA[t][r] = eA;  esA += eA;
        svB[t][r] = eB;  esB += eB;
      }
    esA += __shfl_xor(esA, 16);
    esA += __shfl_xor(esA, 32);
    esB += __shfl_xor(esB, 16);
    esB += __shfl_xor(esB, 32);
    if (lane < 16){
      red2[w * 16 + llo]       = make_float2(pmA, esA);
      red2[128 + w * 16 + llo] = make_float2(pmB, esB);
    }
    asm volatile("s_waitcnt lgkmcnt(0)\n\ts_barrier" ::: "memory");   // b1

    // ---- cross-wave combine (8 waves: 2 reads + shfl over lhi) ----
    float facA, facB;
    {
      float2 c0 = red2[(lhi * 2 + 0) * 16 + llo];
      float2 c1 = red2[(lhi * 2 + 1) * 16 + llo];
      float mg = fmaxf(c0.x, c1.x);
      mg = fmaxf(mg, __shfl_xor(mg, 16));
      mg = fmaxf(mg, __shfl_xor(mg, 32));
      float cg = c0.y * __expf(c0.x - mg) + c1.y * __expf(c1.x - mg);
      cg += __shfl_xor(cg, 16);
      cg += __shfl_xor(cg, 32);
      facA = __expf(pmA - mg) / cg;
    }
    {
      float2 c0 = red2[128 + (lhi * 2 + 0) * 16 + llo];
      float2 c1 = red2[128 + (lhi * 2 + 1) * 16 + llo];
      float mg = fmaxf(c0.x, c1.x);
      mg = fmaxf(mg, __shfl_xor(mg, 16));
      mg = fmaxf(mg, __shfl_xor(mg, 32));
      float cg = c0.y * __expf(c0.x - mg) + c1.y * __expf(c1.x - mg);
      cg += __shfl_xor(cg, 16);
      cg += __shfl_xor(cg, 32);
      facB = __expf(pmB - mg) / cg;
    }

    // ---- p-store + PV: V tile loaded once -> 8 K16 MFMA ----
    float* aRowA = attnF + ((size_t)(n * L_T + row0A + llo)) * L_T;
    float* aRowB = attnF + ((size_t)(n * L_T + row0B + llo)) * L_T;
    const short* VP = (const short*)vpk + (size_t)n * 131072 + w * 1024 + lane * 4;
    f32x4 pA0 = {0,0,0,0}, pA1 = {0,0,0,0}, pA2 = {0,0,0,0}, pA3 = {0,0,0,0};
    f32x4 pB0 = {0,0,0,0}, pB1 = {0,0,0,0}, pB2 = {0,0,0,0}, pB3 = {0,0,0,0};
    #pragma unroll
    for (int t = 0; t < 16; t++){
      short4v v0 = *(const short4v*)(VP + t * 8192 +   0);
      short4v v1 = *(const short4v*)(VP + t * 8192 + 256);
      short4v v2 = *(const short4v*)(VP + t * 8192 + 512);
      short4v v3 = *(const short4v*)(VP + t * 8192 + 768);
      f32x4 pvA, pvB;
      #pragma unroll
      for (int r = 0; r < 4; r++){
        pvA[r] = svA[t][r] * facA;
        pvB[r] = svB[t][r] * facB;
      }
      __builtin_nontemporal_store(pvA, (f32x4*)(aRowA + (w + t * 8) * 16 + lhi * 4));
      __builtin_nontemporal_store(pvB, (f32x4*)(aRowB + (w + t * 8) * 16 + lhi * 4));
      short4v pbA, pbB;
      #pragma unroll
      for (int r = 0; r < 4; r++){
        pbA[r] = (short)f2b(pvA[r]);
        pbB[r] = (short)f2b(pvB[r]);
      }
      pA0 = mfma16k16(v0, pbA, pA0);
      pA1 = mfma16k16(v1, pbA, pA1);
      pA2 = mfma16k16(v2, pbA, pA2);
      pA3 = mfma16k16(v3, pbA, pA3);
      pB0 = mfma16k16(v0, pbB, pB0);
      pB1 = mfma16k16(v1, pbB, pB1);
      pB2 = mfma16k16(v2, pbB, pB2);
      pB3 = mfma16k16(v3, pbB, pB3);
    }

    // ---- cross-wave output reduce via pf: unit A then unit B ----
    float* pfw = pf + w * 1024 + llo * 64;
    *(f32x4*)(pfw + (( 0 + lhi * 4 + llo * 4) & 63)) = pA0;
    *(f32x4*)(pfw + ((16 + lhi * 4 + llo * 4) & 63)) = pA1;
    *(f32x4*)(pfw + ((32 + lhi * 4 + llo * 4) & 63)) = pA2;
    *(f32x4*)(pfw + ((48 + lhi * 4 + llo * 4) & 63)) = pA3;
    asm volatile("s_waitcnt lgkmcnt(0)\n\ts_barrier" ::: "memory");   // b2
    {
      int d = lane;
      int q = w;
      int slot = (d + q * 4) & 63;
      float s = 0.f;
      #pragma unroll
      for (int ww = 0; ww < 8; ww++) s += pf[ww * 1024 + q * 64 + slot];
      outbk[((size_t)(n * L_T + row0A + q)) * HD_T + d] = s;
      int q2 = w + 8;
      int slot2 = (d + q2 * 4) & 63;
      float s2 = 0.f;
      #pragma unroll
      for (int ww = 0; ww < 8; ww++) s2 += pf[ww * 1024 + q2 * 64 + slot2];
      outbk[((size_t)(n * L_T + row0A + q2)) * HD_T + d] = s2;
    }
    asm volatile("s_waitcnt lgkmcnt(0)\n\ts_barrier" ::: "memory");   // b3
    *(f32x4*)(pfw + (( 0 + lhi * 4 + llo * 4) & 63)) = pB0;
    *(f32x4*)(pfw + ((16 + lhi * 4 + llo * 4) & 63)) = pB1;
    *(f32x4*)(pfw + ((32 + lhi * 4 + llo * 4) & 63)) = pB2;
    *(f32x4*)(pfw + ((48 + lhi * 4 + llo * 4) & 63)) = pB3;
    asm volatile("s_waitcnt lgkmcnt(0)\n\ts_barrier" ::: "memory");   // b4
    {
      int d = lane;
      int q = w;
      int slot = (d + q * 4) & 63;
      float s = 0.f;
      #pragma unroll
      for (int ww = 0; ww < 8; ww++) s += pf[ww * 1024 + q * 64 + slot];
      outbk[((size_t)(n * L_T + row0B + q)) * HD_T + d] = s;
      int q2 = w + 8;
      int slot2 = (d + q2 * 4) & 63;
      float s2 = 0.f;
      #pragma unroll
      for (int ww = 0; ww < 8; ww++) s2 += pf[ww * 1024 + q2 * 64 + slot2];
      outbk[((size_t)(n * L_T + row0B + q2)) * HD_T + d] = s2;
    }
  }
}

// ---------- final: y[(l,b)][o] = sum_c outbk_flat[(l,b)][c] * Wo[o][c] ----------
__global__ __launch_bounds__(256) void k_final(const float* __restrict__ outbk,
                                               const unsigned short* __restrict__ Wh,
                                               const unsigned short* __restrict__ Wl,
                                               float* __restrict__ y)
{
  int wv = threadIdx.x >> 6, lane = threadIdx.x & 63;
  int tid = blockIdx.x * 4 + wv;           // 16384 wave-tiles
  int mt = tid >> 5, nt = tid & 31;
  int row0 = mt * 16, col0 = nt * 16;
  int lhi = lane >> 4, llo = lane & 15;
  int arow = row0 + llo;
  int l = arow >> 2, bb = arow & 3;
  const short* WHs = (const short*)Wh;
  const short* WLs = (const short*)Wl;
  f32x4 acc = {0.f, 0.f, 0.f, 0.f};
  for (int k0 = 0; k0 < 512; k0 += 32){
    int c = k0 + lhi * 8;
    const float* ap = outbk + ((size_t)(bb * 8 + (c >> 6)) * L_T + l) * HD_T + (c & 63);
    f32x4 a01 = *(const f32x4*)ap;
    f32x4 a23 = *(const f32x4*)(ap + 4);
    short8 ahi, alo;
    #pragma unroll
    for (int e = 0; e < 4; e++){
      unsigned short h0 = f2b(a01[e]);
      ahi[e] = (short)h0;  alo[e] = (short)f2b(a01[e] - b2f(h0));
      unsigned short h1 = f2b(a23[e]);
      ahi[e + 4] = (short)h1;  alo[e + 4] = (short)f2b(a23[e] - b2f(h1));
    }
    size_t bidx = (size_t)(nt * 16 + (k0 >> 5)) * 512 + lane * 8;
    short8 bh = *(const short8*)(WHs + bidx);
    short8 bl = *(const short8*)(WLs + bidx);
    acc = mfma16(ahi, bh, acc);
    acc = mfma16(alo, bh, acc);
    acc = mfma16(ahi, bl, acc);
  }
  #pragma unroll
  for (int r = 0; r < 4; r++)
    y[(size_t)(row0 + lhi * 4 + r) * 512 + col0 + llo] = acc[r];
}

extern "C" void kernel_launch(void* const* d_in, const int* in_sizes, int n_in,
                              void* d_out, int out_size, void* d_ws, size_t ws_size,
                              hipStream_t stream)
{
  const float* query = (const float*)d_in[0];
  const float* key_t = (const float*)d_in[1];
  const float* value = (const float*)d_in[2];
  const float* kpm   = (const float*)d_in[3];
  const float* qrem  = (const float*)d_in[4];
  const float* Wq    = (const float*)d_in[5];
  const float* Wk    = (const float*)d_in[6];
  const float* Wv    = (const float*)d_in[7];
  const float* Wo    = (const float*)d_in[8];

  float* outY  = (float*)d_out;
  float* attnF = outY + (size_t)L_T * B_T * HID_T;

  char* wp = (char*)d_ws;
  const size_t SZ8M = (size_t)32 * 2048 * 64 * 2;            // 8 MiB
  unsigned short* qhp = (unsigned short*)wp; wp += SZ8M;
  unsigned short* qlp = (unsigned short*)wp; wp += SZ8M;
  unsigned short* khp = (unsigned short*)wp; wp += SZ8M;
  unsigned short* klp = (unsigned short*)wp; wp += SZ8M;
  unsigned short* vpk = (unsigned short*)wp; wp += SZ8M;
  unsigned short* whA = (unsigned short*)wp; wp += (size_t)4 * 512 * 512 * 2;
  unsigned short* wlA = (unsigned short*)wp; wp += (size_t)4 * 512 * 512 * 2;
  float* biasb = (float*)wp; wp += (size_t)32 * 128 * 128 * 4;
  float* outbk = (float*)wp; wp += (size_t)32 * 2048 * 64 * 4;

  const size_t WSTEP = (size_t)512 * 512;

  k_splitW<<<dim3(256, 4), 256, 0, stream>>>(Wq, Wk, Wv, Wo, whA, wlA);
  k_proj3<<<3072, 256, 0, stream>>>(query, key_t, value, whA, wlA,
                                    qhp, qlp, khp, klp, vpk);
  k_tb<<<512, 256, 0, stream>>>(qhp, qlp, Wk, qrem, biasb);
  k_attn<<<256, 512, 0, stream>>>(qhp, qlp, khp, klp, biasb, kpm,
                                  vpk, attnF, outbk);
  k_final<<<4096, 256, 0, stream>>>(outbk, whA + 3 * WSTEP, wlA + 3 * WSTEP, outY);
}

// Round 14
// 460.985 us; speedup vs baseline: 1.0980x; 1.0980x over previous
//
#include <hip/hip_runtime.h>
#include <hip/hip_bf16.h>

// Round 14: k_attn reverted to r12 exact (r13's counted-vmcnt collided with
// outstanding p-STORES -- stores increment vmcnt on CDNA -> forced store
// drains in the QK loop). New k_proj3: stage+convert the 16x512 X-tile ONCE
// per block into stripe-padded LDS fragments (was converted 8x redundantly
// per wave-tile -> VALU-bound at ~430 TF). Bit-identical outputs.

using short8   = __attribute__((ext_vector_type(8))) short;
using short4v  = __attribute__((ext_vector_type(4))) short;
using ushort4v = __attribute__((ext_vector_type(4))) unsigned short;
using f32x4    = __attribute__((ext_vector_type(4))) float;

#define L_T   2048
#define B_T   4
#define HID_T 512
#define HD_T  64
#define LQ_T  128
#define L0_T  1920   // L - LQ

__device__ __forceinline__ float b2f(unsigned short u){
  return __uint_as_float(((unsigned int)u) << 16);
}
__device__ __forceinline__ unsigned short f2b(float f){  // RNE float->bf16
  unsigned int u = __float_as_uint(f);
  u += 0x7FFFu + ((u >> 16) & 1u);
  return (unsigned short)(u >> 16);
}
__device__ __forceinline__ f32x4 mfma16(short8 a, short8 b, f32x4 c){
  return __builtin_amdgcn_mfma_f32_16x16x32_bf16(a, b, c, 0, 0, 0);
}
#if __has_builtin(__builtin_amdgcn_mfma_f32_16x16x16bf16_1k)
__device__ __forceinline__ f32x4 mfma16k16(short4v a, short4v b, f32x4 c){
  return __builtin_amdgcn_mfma_f32_16x16x16bf16_1k(a, b, c, 0, 0, 0);
}
#else
__device__ __forceinline__ f32x4 mfma16k16(short4v a, short4v b, f32x4 c){
  f32x4 d;
  asm("v_mfma_f32_16x16x16_bf16 %0, %1, %2, %0"
      : "=v"(d) : "v"(a), "v"(b), "0"(c));
  return d;
}
#endif

// ---------- split 4 weight matrices f32 -> packed bf16 hi/lo fragments ----
__global__ __launch_bounds__(256) void k_splitW(const float* __restrict__ w0,
                                                const float* __restrict__ w1,
                                                const float* __restrict__ w2,
                                                const float* __restrict__ w3,
                                                unsigned short* __restrict__ hi,
                                                unsigned short* __restrict__ lo)
{
  int wid = blockIdx.y;
  const float* src = (wid == 0) ? w0 : (wid == 1) ? w1 : (wid == 2) ? w2 : w3;
  int chunk = blockIdx.x * 256 + threadIdx.x;      // 65536 chunks
  int o = chunk >> 7;
  int hpos = (chunk & 127) * 4;
  f32x4 v = ((const f32x4*)src)[chunk];
  ushort4v h4, l4;
  #pragma unroll
  for (int e = 0; e < 4; e++){
    unsigned short h = f2b(v[e]);
    h4[e] = h;
    l4[e] = f2b(v[e] - b2f(h));
  }
  size_t idx = ((size_t)(wid * 512 + (o >> 4) * 16 + (hpos >> 5))) * 512
             + (((hpos & 31) >> 3) * 16 + (o & 15)) * 8 + (hpos & 7);
  *(ushort4v*)(hi + idx) = h4;
  *(ushort4v*)(lo + idx) = l4;
}

// ---------- fused projections v2: one (sel, mt) tile per block ----------
// Stage the 16x512 X-tile once: coalesced f32x4 loads, ONE f32->hi/lo
// conversion pass into stripe-padded LDS fragments ([16][520] shorts; pad
// rotates stripe base banks -> write conflicts <=4-way). 4 waves x 2
// col-blocks each compute from LDS A + global W fragments. Outputs
// bit-identical to the r12 version (same slot formula, same MFMA order).
__global__ __launch_bounds__(256) void k_proj3(const float* __restrict__ Xq,
                                               const float* __restrict__ Xk,
                                               const float* __restrict__ Xv,
                                               const unsigned short* __restrict__ WhA,
                                               const unsigned short* __restrict__ WlA,
                                               unsigned short* __restrict__ qhp,
                                               unsigned short* __restrict__ qlp,
                                               unsigned short* __restrict__ khp,
                                               unsigned short* __restrict__ klp,
                                               unsigned short* __restrict__ vpk)
{
  __shared__ short ahl[16][520];
  __shared__ short all_[16][520];
  int sel = blockIdx.x >> 9;               // 0=q, 1=k, 2=v  (1536 blocks)
  int mt  = blockIdx.x & 511;
  const float* X = (sel == 0) ? Xq : (sel == 1) ? Xk : Xv;
  const short* WH = (const short*)WhA + (size_t)sel * 262144;
  const short* WL = (const short*)WlA + (size_t)sel * 262144;
  unsigned short* ohi = (sel == 0) ? qhp : khp;
  unsigned short* olo = (sel == 0) ? qlp : klp;

  // ---- stage + convert A tile (2048 f32x4 chunks, coalesced) ----
  #pragma unroll
  for (int i = 0; i < 8; i++){
    int c = threadIdx.x + 256 * i;
    int row = c >> 7;                      // 0..15
    int k4  = (c & 127) * 4;
    f32x4 v = *(const f32x4*)(X + (size_t)(mt * 16 + row) * 512 + k4);
    ushort4v h4, l4;
    #pragma unroll
    for (int e = 0; e < 4; e++){
      unsigned short h = f2b(v[e]);
      h4[e] = h;
      l4[e] = f2b(v[e] - b2f(h));
    }
    int kk = k4 >> 5;
    int slot = (((k4 & 31) >> 3) * 16 + row) * 8 + (k4 & 7);
    *(ushort4v*)&ahl[kk][slot]  = h4;
    *(ushort4v*)&all_[kk][slot] = l4;
  }
  __syncthreads();

  int wv = threadIdx.x >> 6, lane = threadIdx.x & 63;
  int lhi = lane >> 4, llo = lane & 15;
  int row0 = mt * 16;

  #pragma unroll
  for (int half = 0; half < 2; half++){
    int ntl = wv * 2 + half;               // 0..7
    int col0 = ntl * 64;
    f32x4 acc[4] = {{0,0,0,0},{0,0,0,0},{0,0,0,0},{0,0,0,0}};
    #pragma unroll 4
    for (int kk = 0; kk < 16; kk++){
      short8 ah = *(const short8*)&ahl[kk][lane * 8];
      short8 al = *(const short8*)&all_[kk][lane * 8];
      #pragma unroll
      for (int cb = 0; cb < 4; cb++){
        size_t bidx = (size_t)(((col0 >> 4) + cb) * 16 + kk) * 512 + lane * 8;
        short8 bh = *(const short8*)(WH + bidx);
        short8 bl = *(const short8*)(WL + bidx);
        acc[cb] = mfma16(ah, bh, acc[cb]);
        acc[cb] = mfma16(al, bh, acc[cb]);
        acc[cb] = mfma16(ah, bl, acc[cb]);
      }
    }
    #pragma unroll
    for (int cb = 0; cb < 4; cb++){
      #pragma unroll
      for (int r = 0; r < 4; r++){
        int row = row0 + lhi * 4 + r;      // flat (l,b)
        int o   = col0 + cb * 16 + llo;
        int l = row >> 2, bb = row & 3;
        int n = bb * 8 + (o >> 6), d = o & 63;
        float v = acc[cb][r];
        if (sel != 2){
          size_t idx = ((size_t)(n * 128 + (l >> 4)) * 2 + (d >> 5)) * 512
                     + (((d & 31) >> 3) * 16 + (l & 15)) * 8 + (d & 7);
          unsigned short h = f2b(v);
          ohi[idx] = h;
          olo[idx] = f2b(v - b2f(h));
        } else {
          int m = l;
          size_t idx = (((size_t)(n * 128 + (m >> 4)) * 4) + (d >> 4)) * 256
                     + ((m & 15) >> 2) * 64 + (d & 15) * 4 + (m & 3);
          vpk[idx] = f2b(v);
        }
      }
    }
  }
}

// ---------- merged t + bias:  per block (bb, i) ----------
__global__ __launch_bounds__(256) void k_tb(const unsigned short* __restrict__ qhp,
                                            const unsigned short* __restrict__ qlp,
                                            const float* __restrict__ Wk,
                                            const float* __restrict__ qrem,
                                            float* __restrict__ bias)
{
  int bb = blockIdx.x & 3, i = blockIdx.x >> 2;
  __shared__ float qv[8][64];
  __shared__ float ts[8][512];
  for (int idx = threadIdx.x; idx < 512; idx += 256){
    int kh = idx >> 6, d = idx & 63;
    int n = bb * 8 + kh;
    int row = L0_T + i;
    size_t qidx = ((size_t)(n * 128 + (row >> 4)) * 2 + (d >> 5)) * 512
                + (((d & 31) >> 3) * 16 + (row & 15)) * 8 + (d & 7);
    qv[kh][d] = b2f(qhp[qidx]) + b2f(qlp[qidx]);
  }
  __syncthreads();
  {
    int kh = threadIdx.x >> 5, h0 = (threadIdx.x & 31) * 16;
    f32x4 a0 = {0,0,0,0}, a1 = {0,0,0,0}, a2 = {0,0,0,0}, a3 = {0,0,0,0};
    for (int d = 0; d < 64; d++){
      float qd = qv[kh][d];
      const float* wr = Wk + (size_t)(kh * 64 + d) * 512 + h0;
      a0 += qd * *(const f32x4*)(wr);
      a1 += qd * *(const f32x4*)(wr + 4);
      a2 += qd * *(const f32x4*)(wr + 8);
      a3 += qd * *(const f32x4*)(wr + 12);
    }
    *(f32x4*)&ts[kh][h0]      = a0;
    *(f32x4*)&ts[kh][h0 + 4]  = a1;
    *(f32x4*)&ts[kh][h0 + 8]  = a2;
    *(f32x4*)&ts[kh][h0 + 12] = a3;
  }
  __syncthreads();
  int wv = threadIdx.x >> 6, lane = threadIdx.x & 63;
  for (int j = wv; j < 128; j += 4){
    const float* qr = qrem + (((size_t)i * LQ_T + j) * B_T + bb) * 512;
    f32x4 v0 = *(const f32x4*)(qr + lane * 4);
    f32x4 v1 = *(const f32x4*)(qr + 256 + lane * 4);
    float pl[8];
    #pragma unroll
    for (int kh = 0; kh < 8; kh++){
      f32x4 t0 = *(const f32x4*)&ts[kh][lane * 4];
      f32x4 t1 = *(const f32x4*)&ts[kh][256 + lane * 4];
      pl[kh] = v0[0]*t0[0] + v0[1]*t0[1] + v0[2]*t0[2] + v0[3]*t0[3]
             + v1[0]*t1[0] + v1[1]*t1[1] + v1[2]*t1[2] + v1[3]*t1[3];
    }
    #pragma unroll
    for (int kh = 0; kh < 8; kh++){
      float s = pl[kh];
      #pragma unroll
      for (int msk = 1; msk < 64; msk <<= 1) s += __shfl_xor(s, msk);
      pl[kh] = s;
    }
    if (lane == 0){
      #pragma unroll
      for (int kh = 0; kh < 8; kh++)
        bias[((size_t)(bb * 8 + kh) * LQ_T + i) * LQ_T + j] = pl[kh];
    }
  }
}

// ---------- fused QK^T(swapped) + bias + mask + softmax + p-store + PV ----------
// r12 exact: 512 threads / 8 waves, 2 units per pass, waves_per_eu(2,2).
__attribute__((amdgpu_waves_per_eu(2, 2)))
__global__ __launch_bounds__(512) void k_attn(
    const unsigned short* __restrict__ qhp, const unsigned short* __restrict__ qlp,
    const unsigned short* __restrict__ khp, const unsigned short* __restrict__ klp,
    const float* __restrict__ bias, const float* __restrict__ kpm,
    const unsigned short* __restrict__ vpk,
    float* __restrict__ attnF, float* __restrict__ outbk)
{
  __shared__ __attribute__((aligned(16))) float pf[8 * 1024];    // 32 KB
  __shared__ float2 red2[2 * 128];                               // 2 KB
  const int w = threadIdx.x >> 6, lane = threadIdx.x & 63;
  const int lhi = lane >> 4, llo = lane & 15;

  for (int j = 0; j < 8; ++j){
    const int p = blockIdx.x + (j << 8);   // 4 heads live per phase
    const int n = p >> 6, rbp = p & 63;
    const int rbA = rbp * 2, rbB = rbA + 1;
    const int row0A = rbA * 16, row0B = rbB * 16, bb = n >> 3;

    const short* QHA = (const short*)qhp + ((size_t)(n * 128 + rbA) * 2) * 512 + lane * 8;
    const short* QLA = (const short*)qlp + ((size_t)(n * 128 + rbA) * 2) * 512 + lane * 8;
    const short* QHB = (const short*)qhp + ((size_t)(n * 128 + rbB) * 2) * 512 + lane * 8;
    const short* QLB = (const short*)qlp + ((size_t)(n * 128 + rbB) * 2) * 512 + lane * 8;
    short8 qhA0 = *(const short8*)(QHA);
    short8 qhA1 = *(const short8*)(QHA + 512);
    short8 qlA0 = *(const short8*)(QLA);
    short8 qlA1 = *(const short8*)(QLA + 512);
    short8 qhB0 = *(const short8*)(QHB);
    short8 qhB1 = *(const short8*)(QHB + 512);
    short8 qlB0 = *(const short8*)(QLB);
    short8 qlB1 = *(const short8*)(QLB + 512);
    const short* KH = (const short*)khp + (size_t)n * 131072 + w * 1024 + lane * 8;
    const short* KL = (const short*)klp + (size_t)n * 131072 + w * 1024 + lane * 8;

    // ---- QK^T: tile = w + 8t; K pair loaded once -> 12 MFMA ----
    float svA[16][4], svB[16][4];
    #pragma unroll
    for (int t = 0; t < 16; t++){
      short8 kh0v = *(const short8*)(KH + t * 8192);
      short8 kh1v = *(const short8*)(KH + t * 8192 + 512);
      short8 kl0v = *(const short8*)(KL + t * 8192);
      short8 kl1v = *(const short8*)(KL + t * 8192 + 512);
      f32x4 aA = {0.f, 0.f, 0.f, 0.f};
      f32x4 aB = {0.f, 0.f, 0.f, 0.f};
      aA = mfma16(kh0v, qhA0, aA);
      aA = mfma16(kl0v, qhA0, aA);
      aA = mfma16(kh0v, qlA0, aA);
      aA = mfma16(kh1v, qhA1, aA);
      aA = mfma16(kl1v, qhA1, aA);
      aA = mfma16(kh1v, qlA1, aA);
      aB = mfma16(kh0v, qhB0, aB);
      aB = mfma16(kl0v, qhB0, aB);
      aB = mfma16(kh0v, qlB0, aB);
      aB = mfma16(kh1v, qhB1, aB);
      aB = mfma16(kl1v, qhB1, aB);
      aB = mfma16(kh1v, qlB1, aB);
      if (t == 15 && rbp >= 60){           // tiles 120..127 = (t=15, all w)
        int j0 = w * 16 + lhi * 4;
        int iA = row0A - L0_T + llo;
        int iB = row0B - L0_T + llo;
        aA += *(const f32x4*)(bias + ((size_t)(n * 128 + iA)) * 128 + j0);
        aB += *(const f32x4*)(bias + ((size_t)(n * 128 + iB)) * 128 + j0);
      }
      f32x4 mkv = *(const f32x4*)(kpm + bb * 2048 + (w + t * 8) * 16 + lhi * 4);
      #pragma unroll
      for (int r = 0; r < 4; r++){
        float mk = (mkv[r] != 0.f) ? -__builtin_inff() : 0.f;
        svA[t][r] = aA[r] * 0.125f + mk;
        svB[t][r] = aB[r] * 0.125f + mk;
      }
    }

    // ---- wave-level (max, expsum) per q = llo ----
    float pmA = svA[0][0], pmB = svB[0][0];
    #pragma unroll
    for (int t = 0; t < 16; t++)
      #pragma unroll
      for (int r = 0; r < 4; r++){
        pmA = fmaxf(pmA, svA[t][r]);
        pmB = fmaxf(pmB, svB[t][r]);
      }
    pmA = fmaxf(pmA, __shfl_xor(pmA, 16));
    pmA = fmaxf(pmA, __shfl_xor(pmA, 32));
    pmB = fmaxf(pmB, __shfl_xor(pmB, 16));
    pmB = fmaxf(pmB, __shfl_xor(pmB, 32));
    float esA = 0.f, esB = 0.f;
    #pragma unroll
    for (int t = 0; t < 16; t++)
      #pragma unroll
      for (int r = 0; r < 4; r++){
        float eA = __expf(svA[t][r] - pmA);
        float eB = __expf(svB[t][r] - pmB);
        svA[t][r] = eA;  esA += eA;
        svB[t][r] = eB;  esB += eB;
      }
    esA += __shfl_xor(esA, 16);
    esA += __shfl_xor(esA, 32);
    esB += __shfl_xor(esB, 16);
    esB += __shfl_xor(esB, 32);
    if (lane < 16){
      red2[w * 16 + llo]       = make_float2(pmA, esA);
      red2[128 + w * 16 + llo] = make_float2(pmB, esB);
    }
    asm volatile("s_waitcnt lgkmcnt(0)\n\ts_barrier" ::: "memory");   // b1

    // ---- cross-wave combine (8 waves: 2 reads + shfl over lhi) ----
    float facA, facB;
    {
      float2 c0 = red2[(lhi * 2 + 0) * 16 + llo];
      float2 c1 = red2[(lhi * 2 + 1) * 16 + llo];
      float mg = fmaxf(c0.x, c1.x);
      mg = fmaxf(mg, __shfl_xor(mg, 16));
      mg = fmaxf(mg, __shfl_xor(mg, 32));
      float cg = c0.y * __expf(c0.x - mg) + c1.y * __expf(c1.x - mg);
      cg += __shfl_xor(cg, 16);
      cg += __shfl_xor(cg, 32);
      facA = __expf(pmA - mg) / cg;
    }
    {
      float2 c0 = red2[128 + (lhi * 2 + 0) * 16 + llo];
      float2 c1 = red2[128 + (lhi * 2 + 1) * 16 + llo];
      float mg = fmaxf(c0.x, c1.x);
      mg = fmaxf(mg, __shfl_xor(mg, 16));
      mg = fmaxf(mg, __shfl_xor(mg, 32));
      float cg = c0.y * __expf(c0.x - mg) + c1.y * __expf(c1.x - mg);
      cg += __shfl_xor(cg, 16);
      cg += __shfl_xor(cg, 32);
      facB = __expf(pmB - mg) / cg;
    }

    // ---- p-store + PV: V tile loaded once -> 8 K16 MFMA ----
    float* aRowA = attnF + ((size_t)(n * L_T + row0A + llo)) * L_T;
    float* aRowB = attnF + ((size_t)(n * L_T + row0B + llo)) * L_T;
    const short* VP = (const short*)vpk + (size_t)n * 131072 + w * 1024 + lane * 4;
    f32x4 pA0 = {0,0,0,0}, pA1 = {0,0,0,0}, pA2 = {0,0,0,0}, pA3 = {0,0,0,0};
    f32x4 pB0 = {0,0,0,0}, pB1 = {0,0,0,0}, pB2 = {0,0,0,0}, pB3 = {0,0,0,0};
    #pragma unroll
    for (int t = 0; t < 16; t++){
      short4v v0 = *(const short4v*)(VP + t * 8192 +   0);
      short4v v1 = *(const short4v*)(VP + t * 8192 + 256);
      short4v v2 = *(const short4v*)(VP + t * 8192 + 512);
      short4v v3 = *(const short4v*)(VP + t * 8192 + 768);
      f32x4 pvA, pvB;
      #pragma unroll
      for (int r = 0; r < 4; r++){
        pvA[r] = svA[t][r] * facA;
        pvB[r] = svB[t][r] * facB;
      }
      __builtin_nontemporal_store(pvA, (f32x4*)(aRowA + (w + t * 8) * 16 + lhi * 4));
      __builtin_nontemporal_store(pvB, (f32x4*)(aRowB + (w + t * 8) * 16 + lhi * 4));
      short4v pbA, pbB;
      #pragma unroll
      for (int r = 0; r < 4; r++){
        pbA[r] = (short)f2b(pvA[r]);
        pbB[r] = (short)f2b(pvB[r]);
      }
      pA0 = mfma16k16(v0, pbA, pA0);
      pA1 = mfma16k16(v1, pbA, pA1);
      pA2 = mfma16k16(v2, pbA, pA2);
      pA3 = mfma16k16(v3, pbA, pA3);
      pB0 = mfma16k16(v0, pbB, pB0);
      pB1 = mfma16k16(v1, pbB, pB1);
      pB2 = mfma16k16(v2, pbB, pB2);
      pB3 = mfma16k16(v3, pbB, pB3);
    }

    // ---- cross-wave output reduce via pf: unit A then unit B ----
    float* pfw = pf + w * 1024 + llo * 64;
    *(f32x4*)(pfw + (( 0 + lhi * 4 + llo * 4) & 63)) = pA0;
    *(f32x4*)(pfw + ((16 + lhi * 4 + llo * 4) & 63)) = pA1;
    *(f32x4*)(pfw + ((32 + lhi * 4 + llo * 4) & 63)) = pA2;
    *(f32x4*)(pfw + ((48 + lhi * 4 + llo * 4) & 63)) = pA3;
    asm volatile("s_waitcnt lgkmcnt(0)\n\ts_barrier" ::: "memory");   // b2
    {
      int d = lane;
      int q = w;
      int slot = (d + q * 4) & 63;
      float s = 0.f;
      #pragma unroll
      for (int ww = 0; ww < 8; ww++) s += pf[ww * 1024 + q * 64 + slot];
      outbk[((size_t)(n * L_T + row0A + q)) * HD_T + d] = s;
      int q2 = w + 8;
      int slot2 = (d + q2 * 4) & 63;
      float s2 = 0.f;
      #pragma unroll
      for (int ww = 0; ww < 8; ww++) s2 += pf[ww * 1024 + q2 * 64 + slot2];
      outbk[((size_t)(n * L_T + row0A + q2)) * HD_T + d] = s2;
    }
    asm volatile("s_waitcnt lgkmcnt(0)\n\ts_barrier" ::: "memory");   // b3
    *(f32x4*)(pfw + (( 0 + lhi * 4 + llo * 4) & 63)) = pB0;
    *(f32x4*)(pfw + ((16 + lhi * 4 + llo * 4) & 63)) = pB1;
    *(f32x4*)(pfw + ((32 + lhi * 4 + llo * 4) & 63)) = pB2;
    *(f32x4*)(pfw + ((48 + lhi * 4 + llo * 4) & 63)) = pB3;
    asm volatile("s_waitcnt lgkmcnt(0)\n\ts_barrier" ::: "memory");   // b4
    {
      int d = lane;
      int q = w;
      int slot = (d + q * 4) & 63;
      float s = 0.f;
      #pragma unroll
      for (int ww = 0; ww < 8; ww++) s += pf[ww * 1024 + q * 64 + slot];
      outbk[((size_t)(n * L_T + row0B + q)) * HD_T + d] = s;
      int q2 = w + 8;
      int slot2 = (d + q2 * 4) & 63;
      float s2 = 0.f;
      #pragma unroll
      for (int ww = 0; ww < 8; ww++) s2 += pf[ww * 1024 + q2 * 64 + slot2];
      outbk[((size_t)(n * L_T + row0B + q2)) * HD_T + d] = s2;
    }
  }
}

// ---------- final: y[(l,b)][o] = sum_c outbk_flat[(l,b)][c] * Wo[o][c] ----------
__global__ __launch_bounds__(256) void k_final(const float* __restrict__ outbk,
                                               const unsigned short* __restrict__ Wh,
                                               const unsigned short* __restrict__ Wl,
                                               float* __restrict__ y)
{
  int wv = threadIdx.x >> 6, lane = threadIdx.x & 63;
  int tid = blockIdx.x * 4 + wv;           // 16384 wave-tiles
  int mt = tid >> 5, nt = tid & 31;
  int row0 = mt * 16, col0 = nt * 16;
  int lhi = lane >> 4, llo = lane & 15;
  int arow = row0 + llo;
  int l = arow >> 2, bb = arow & 3;
  const short* WHs = (const short*)Wh;
  const short* WLs = (const short*)Wl;
  f32x4 acc = {0.f, 0.f, 0.f, 0.f};
  for (int k0 = 0; k0 < 512; k0 += 32){
    int c = k0 + lhi * 8;
    const float* ap = outbk + ((size_t)(bb * 8 + (c >> 6)) * L_T + l) * HD_T + (c & 63);
    f32x4 a01 = *(const f32x4*)ap;
    f32x4 a23 = *(const f32x4*)(ap + 4);
    short8 ahi, alo;
    #pragma unroll
    for (int e = 0; e < 4; e++){
      unsigned short h0 = f2b(a01[e]);
      ahi[e] = (short)h0;  alo[e] = (short)f2b(a01[e] - b2f(h0));
      unsigned short h1 = f2b(a23[e]);
      ahi[e + 4] = (short)h1;  alo[e + 4] = (short)f2b(a23[e] - b2f(h1));
    }
    size_t bidx = (size_t)(nt * 16 + (k0 >> 5)) * 512 + lane * 8;
    short8 bh = *(const short8*)(WHs + bidx);
    short8 bl = *(const short8*)(WLs + bidx);
    acc = mfma16(ahi, bh, acc);
    acc = mfma16(alo, bh, acc);
    acc = mfma16(ahi, bl, acc);
  }
  #pragma unroll
  for (int r = 0; r < 4; r++)
    y[(size_t)(row0 + lhi * 4 + r) * 512 + col0 + llo] = acc[r];
}

extern "C" void kernel_launch(void* const* d_in, const int* in_sizes, int n_in,
                              void* d_out, int out_size, void* d_ws, size_t ws_size,
                              hipStream_t stream)
{
  const float* query = (const float*)d_in[0];
  const float* key_t = (const float*)d_in[1];
  const float* value = (const float*)d_in[2];
  const float* kpm   = (const float*)d_in[3];
  const float* qrem  = (const float*)d_in[4];
  const float* Wq    = (const float*)d_in[5];
  const float* Wk    = (const float*)d_in[6];
  const float* Wv    = (const float*)d_in[7];
  const float* Wo    = (const float*)d_in[8];

  float* outY  = (float*)d_out;
  float* attnF = outY + (size_t)L_T * B_T * HID_T;

  char* wp = (char*)d_ws;
  const size_t SZ8M = (size_t)32 * 2048 * 64 * 2;            // 8 MiB
  unsigned short* qhp = (unsigned short*)wp; wp += SZ8M;
  unsigned short* qlp = (unsigned short*)wp; wp += SZ8M;
  unsigned short* khp = (unsigned short*)wp; wp += SZ8M;
  unsigned short* klp = (unsigned short*)wp; wp += SZ8M;
  unsigned short* vpk = (unsigned short*)wp; wp += SZ8M;
  unsigned short* whA = (unsigned short*)wp; wp += (size_t)4 * 512 * 512 * 2;
  unsigned short* wlA = (unsigned short*)wp; wp += (size_t)4 * 512 * 512 * 2;
  float* biasb = (float*)wp; wp += (size_t)32 * 128 * 128 * 4;
  float* outbk = (float*)wp; wp += (size_t)32 * 2048 * 64 * 4;

  const size_t WSTEP = (size_t)512 * 512;

  k_splitW<<<dim3(256, 4), 256, 0, stream>>>(Wq, Wk, Wv, Wo, whA, wlA);
  k_proj3<<<1536, 256, 0, stream>>>(query, key_t, value, whA, wlA,
                                    qhp, qlp, khp, klp, vpk);
  k_tb<<<512, 256, 0, stream>>>(qhp, qlp, Wk, qrem, biasb);
  k_attn<<<256, 512, 0, stream>>>(qhp, qlp, khp, klp, biasb, kpm,
                                  vpk, attnF, outbk);
  k_final<<<4096, 256, 0, stream>>>(outbk, whA + 3 * WSTEP, wlA + 3 * WSTEP, outY);
}